// Round 5
// baseline (4856.792 us; speedup 1.0000x reference)
//
#include <hip/hip_runtime.h>
#include <cstdint>

#define N_PTS   8192
#define S_PTS   2048
#define K_SMP   32
#define BATCH   8
#define P_TOT   (BATCH*S_PTS*K_SMP)   /* 524288 */
#define R2      0.16f
#define CNT_INV (1.0f/524288.0f)

// Unfused: matches numpy-f32 elementwise square + sequential 3-sum.
__device__ __forceinline__ float sqd(float ax, float ay, float az,
                                     float bx, float by, float bz) {
    float dx = __fsub_rn(ax, bx), dy = __fsub_rn(ay, by), dz = __fsub_rn(az, bz);
    return __fadd_rn(__fadd_rn(__fmul_rn(dx, dx), __fmul_rn(dy, dy)), __fmul_rn(dz, dz));
}

// ---------------------------------------------------------------- FPS (verified by Output 0 in rounds 3+4)
__global__ __launch_bounds__(512) void fps_kernel(const float* __restrict__ xyz,
                                                  float* __restrict__ newxyz) {
    __shared__ float sx[N_PTS], sy[N_PTS], sz[N_PTS];          // 96 KiB
    __shared__ unsigned long long s_keys[S_PTS];               // 16 KiB

    const int b = blockIdx.x, t = threadIdx.x;
    const float* xb = xyz + (size_t)b * 3 * N_PTS;
    const int base = t * 16;

    float px[16], py[16], pz[16], dist[16];
#pragma unroll
    for (int q = 0; q < 4; q++) {
        float4 vx = *(const float4*)(xb + base + 4 * q);
        float4 vy = *(const float4*)(xb + N_PTS + base + 4 * q);
        float4 vz = *(const float4*)(xb + 2 * N_PTS + base + 4 * q);
        px[4*q] = vx.x; px[4*q+1] = vx.y; px[4*q+2] = vx.z; px[4*q+3] = vx.w;
        py[4*q] = vy.x; py[4*q+1] = vy.y; py[4*q+2] = vy.z; py[4*q+3] = vy.w;
        pz[4*q] = vz.x; pz[4*q+1] = vz.y; pz[4*q+2] = vz.z; pz[4*q+3] = vz.w;
    }
#pragma unroll
    for (int j = 0; j < 16; j++) {
        sx[base+j] = px[j]; sy[base+j] = py[j]; sz[base+j] = pz[j];
        dist[j] = 1e10f;
    }
    for (int i = t; i < S_PTS; i += 512) s_keys[i] = 0ull;
    __syncthreads();

    int last = 0;
    for (int i = 1; i < S_PTS; i++) {
        float lx = sx[last], ly = sy[last], lz = sz[last];
        float bv = -1.0f; int bi = 0;
#pragma unroll
        for (int j = 0; j < 16; j++) {
            float d  = sqd(px[j], py[j], pz[j], lx, ly, lz);
            float nd = fminf(dist[j], d);
            dist[j] = nd;
            if (nd > bv) { bv = nd; bi = base + j; }
        }
#pragma unroll
        for (int off = 1; off <= 32; off <<= 1) {
            float ov = __shfl_xor(bv, off);
            int   oi = __shfl_xor(bi, off);
            if (ov > bv || (ov == bv && oi < bi)) { bv = ov; bi = oi; }
        }
        if ((t & 63) == 0)
            atomicMax(&s_keys[i],
                      ((unsigned long long)__float_as_uint(bv) << 32)
                      | (unsigned long long)(0xFFFFFFFFu - (unsigned)bi));
        __syncthreads();
        last = (int)(0xFFFFFFFFu - (unsigned)(s_keys[i] & 0xFFFFFFFFull)) & (N_PTS - 1);
    }
    __syncthreads();
    for (int s = t; s < S_PTS; s += 512) {
        int id = (s == 0) ? 0
               : (int)(0xFFFFFFFFu - (unsigned)(s_keys[s] & 0xFFFFFFFFull)) & (N_PTS - 1);
        newxyz[((size_t)b*3 + 0) * S_PTS + s] = sx[id];
        newxyz[((size_t)b*3 + 1) * S_PTS + s] = sy[id];
        newxyz[((size_t)b*3 + 2) * S_PTS + s] = sz[id];
    }
}

// ---------------------------------------------------------------- ball query (semantics proven vs argsort form)
__global__ __launch_bounds__(256) void ball_kernel(const float* __restrict__ xyz,
                                                   const float* __restrict__ newxyz,
                                                   int* __restrict__ ballidx) {
    int g    = blockIdx.x * 4 + (threadIdx.x >> 6);
    int lane = threadIdx.x & 63;
    int b = g >> 11, s = g & 2047;
    const float* xb = xyz + (size_t)b * 3 * N_PTS;
    float cx = newxyz[((size_t)b*3 + 0) * S_PTS + s];
    float cy = newxyz[((size_t)b*3 + 1) * S_PTS + s];
    float cz = newxyz[((size_t)b*3 + 2) * S_PTS + s];
    int* outp = ballidx + (size_t)g * K_SMP;

    int cnt = 0, first = 0;  bool have_first = false;
    for (int n0 = 0; n0 < N_PTS; n0 += 64) {
        int n = n0 + lane;
        float d = sqd(cx, cy, cz, xb[n], xb[N_PTS + n], xb[2*N_PTS + n]);
        bool in = (d <= R2);
        unsigned long long m = __ballot(in);
        if (in) {
            int pos = cnt + __popcll(m & ((1ull << lane) - 1ull));
            if (pos < K_SMP) outp[pos] = n;
        }
        if (!have_first && m != 0ull) { first = n0 + (int)__builtin_ctzll(m); have_first = true; }
        cnt += __popcll(m);
        if (cnt >= K_SMP) break;
    }
    if (cnt < K_SMP && lane < K_SMP && lane >= cnt) outp[lane] = first;
}

// ---------------------------------------------------------------- DUMB PIPELINE (bisection build)
// D1: gather + conv1 -> x1 rows. One thread per position. Weights in LDS in
// DIRECT layout (uniform broadcast reads, conflict-free).
__global__ __launch_bounds__(256) void d_conv1(const float* __restrict__ xyz,
                                               const float* __restrict__ points,
                                               const float* __restrict__ newxyz,
                                               const int* __restrict__ ballidx,
                                               const float* __restrict__ w1,
                                               const float* __restrict__ b1,
                                               float* __restrict__ xbuf) {
    __shared__ float sw[64 * 9];
    __shared__ float sb[64];
    int t = threadIdx.x;
    for (int i = t; i < 576; i += 256) sw[i] = w1[i];
    if (t < 64) sb[t] = b1[t];
    __syncthreads();

    int p = blockIdx.x * 256 + t;
    int g = p >> 5, b = g >> 11, s = g & 2047;
    int idx = ballidx[p] & (N_PTS - 1);
    const float* xb = xyz    + (size_t)b * 3 * N_PTS;
    const float* pb = points + (size_t)b * 6 * N_PTS;
    float f[9];
    f[0] = xb[idx]           - newxyz[((size_t)b*3 + 0) * S_PTS + s];
    f[1] = xb[N_PTS + idx]   - newxyz[((size_t)b*3 + 1) * S_PTS + s];
    f[2] = xb[2*N_PTS + idx] - newxyz[((size_t)b*3 + 2) * S_PTS + s];
#pragma unroll
    for (int c = 0; c < 6; c++) f[3 + c] = pb[c * N_PTS + idx];

    float* row = xbuf + (size_t)p * 64;
    for (int co = 0; co < 64; co++) {
        float a = sb[co];
#pragma unroll
        for (int c = 0; c < 9; c++) a += sw[co * 9 + c] * f[c];
        row[co] = a;
    }
}

// D2: per-channel sum/sumsq over (P, C) rows. Trivial mapping, coalesced.
template <int C>
__global__ __launch_bounds__(256) void d_stats(const float* __restrict__ x,
                                               float* __restrict__ gstat) {
    __shared__ float ss[C], sq[C];
    int t = threadIdx.x;
    for (int i = t; i < C; i += 256) { ss[i] = 0.f; sq[i] = 0.f; }
    __syncthreads();
    int c = t & (C - 1), r0 = t / C;
    const int RPI = 256 / C;
    float s = 0.f, q = 0.f;
    size_t base = (size_t)blockIdx.x * 256;   // 2048 blocks x 256 rows = P_TOT
    for (int r = r0; r < 256; r += RPI) {
        float v = x[(base + r) * C + c];
        s += v; q += v * v;
    }
    atomicAdd(&ss[c], s); atomicAdd(&sq[c], q);
    __syncthreads();
    for (int i = t; i < C; i += 256) { atomicAdd(&gstat[i], ss[i]); atomicAdd(&gstat[C + i], sq[i]); }
}

// D3: BN1+relu then conv2, IN PLACE per row (read full row first, then write).
__global__ __launch_bounds__(256) void d_conv2(float* __restrict__ xbuf,
                                               const float* __restrict__ AB1,
                                               const float* __restrict__ w2,
                                               const float* __restrict__ b2) {
    __shared__ float sw[64 * 64];     // w2 direct [co][c]
    __shared__ float sA[64], sB[64], sb[64];
    int t = threadIdx.x;
    for (int i = t; i < 4096; i += 256) sw[i] = w2[i];
    if (t < 64) { sA[t] = AB1[t]; sB[t] = AB1[64 + t]; sb[t] = b2[t]; }
    __syncthreads();

    size_t p = (size_t)blockIdx.x * 256 + t;
    float* row = xbuf + p * 64;
    float y[64];
#pragma unroll
    for (int c = 0; c < 64; c += 4) {
        float4 v = *(const float4*)(row + c);
        y[c]   = fmaxf(0.f, v.x * sA[c]   + sB[c]);
        y[c+1] = fmaxf(0.f, v.y * sA[c+1] + sB[c+1]);
        y[c+2] = fmaxf(0.f, v.z * sA[c+2] + sB[c+2]);
        y[c+3] = fmaxf(0.f, v.w * sA[c+3] + sB[c+3]);
    }
    for (int co0 = 0; co0 < 64; co0 += 16) {
        float o[16];
#pragma unroll
        for (int co = 0; co < 16; co++) {
            float a = sb[co0 + co];
#pragma unroll
            for (int c = 0; c < 64; c += 4) {
                float4 w = *(const float4*)&sw[(co0 + co) * 64 + c];
                a += w.x * y[c] + w.y * y[c+1] + w.z * y[c+2] + w.w * y[c+3];
            }
            o[co] = a;
        }
#pragma unroll
        for (int co = 0; co < 16; co += 4)
            *(float4*)(row + co0 + co) = make_float4(o[co], o[co+1], o[co+2], o[co+3]);
    }
}

// D4: BN2+relu + conv3 raw -> per-channel stats (rotated LDS atomics).
__global__ __launch_bounds__(256) void d_conv3_stats(const float* __restrict__ xbuf,
                                                     const float* __restrict__ AB2,
                                                     const float* __restrict__ w3,
                                                     const float* __restrict__ b3,
                                                     float* __restrict__ gstat) {
    __shared__ float sw[128 * 64];    // w3 direct [ch][c], 32 KiB
    __shared__ float sA[64], sB[64], sb3[128], ss[128], sq[128];
    int t = threadIdx.x, lane = t & 63;
    for (int i = t; i < 8192; i += 256) sw[i] = w3[i];
    if (t < 64) { sA[t] = AB2[t]; sB[t] = AB2[64 + t]; }
    if (t < 128) { sb3[t] = b3[t]; ss[t] = 0.f; sq[t] = 0.f; }
    __syncthreads();

    size_t p = (size_t)blockIdx.x * 256 + t;
    const float* row = xbuf + p * 64;
    float y[64];
#pragma unroll
    for (int c = 0; c < 64; c += 4) {
        float4 v = *(const float4*)(row + c);
        y[c]   = fmaxf(0.f, v.x * sA[c]   + sB[c]);
        y[c+1] = fmaxf(0.f, v.y * sA[c+1] + sB[c+1]);
        y[c+2] = fmaxf(0.f, v.z * sA[c+2] + sB[c+2]);
        y[c+3] = fmaxf(0.f, v.w * sA[c+3] + sB[c+3]);
    }
    for (int ch0 = 0; ch0 < 128; ch0 += 16) {
        float o[16];
#pragma unroll
        for (int ch = 0; ch < 16; ch++) {
            float a = sb3[ch0 + ch];
#pragma unroll
            for (int c = 0; c < 64; c += 4) {
                float4 w = *(const float4*)&sw[(ch0 + ch) * 64 + c];
                a += w.x * y[c] + w.y * y[c+1] + w.z * y[c+2] + w.w * y[c+3];
            }
            o[ch] = a;
        }
        // rotate atomic target by lane to spread LDS bank pressure
#pragma unroll
        for (int i = 0; i < 16; i++) {
            int j = (i + lane) & 15;
            atomicAdd(&ss[ch0 + j], o[j]);
            atomicAdd(&sq[ch0 + j], o[j] * o[j]);
        }
    }
    __syncthreads();
    if (t < 128) { atomicAdd(&gstat[t], ss[t]); atomicAdd(&gstat[128 + t], sq[t]); }
}

// D5: BN2+relu + conv3 + BN3+relu + max over K via LDS uint atomicMax
// (valid: relu output >= 0 -> float bits monotonic).
__global__ __launch_bounds__(256) void d_conv3_max(const float* __restrict__ xbuf,
                                                   const float* __restrict__ AB2,
                                                   const float* __restrict__ w3,
                                                   const float* __restrict__ b3,
                                                   const float* __restrict__ AB3,
                                                   float* __restrict__ out_np) {
    __shared__ float sw[128 * 64];
    __shared__ float sA[64], sB[64], sb3[128], sA3[128], sB3[128];
    __shared__ unsigned int smax[8][128];
    int t = threadIdx.x, lane = t & 63;
    for (int i = t; i < 8192; i += 256) sw[i] = w3[i];
    if (t < 64) { sA[t] = AB2[t]; sB[t] = AB2[64 + t]; }
    if (t < 128) { sb3[t] = b3[t]; sA3[t] = AB3[t]; sB3[t] = AB3[128 + t]; }
    for (int i = t; i < 1024; i += 256) smax[i >> 7][i & 127] = 0u;
    __syncthreads();

    size_t p = (size_t)blockIdx.x * 256 + t;
    int gl = t >> 5;                       // local group 0..7 (p>>5 within block)
    const float* row = xbuf + p * 64;
    float y[64];
#pragma unroll
    for (int c = 0; c < 64; c += 4) {
        float4 v = *(const float4*)(row + c);
        y[c]   = fmaxf(0.f, v.x * sA[c]   + sB[c]);
        y[c+1] = fmaxf(0.f, v.y * sA[c+1] + sB[c+1]);
        y[c+2] = fmaxf(0.f, v.z * sA[c+2] + sB[c+2]);
        y[c+3] = fmaxf(0.f, v.w * sA[c+3] + sB[c+3]);
    }
    for (int ch0 = 0; ch0 < 128; ch0 += 16) {
        float o[16];
#pragma unroll
        for (int ch = 0; ch < 16; ch++) {
            float a = sb3[ch0 + ch];
#pragma unroll
            for (int c = 0; c < 64; c += 4) {
                float4 w = *(const float4*)&sw[(ch0 + ch) * 64 + c];
                a += w.x * y[c] + w.y * y[c+1] + w.z * y[c+2] + w.w * y[c+3];
            }
            o[ch] = a;
        }
#pragma unroll
        for (int i = 0; i < 16; i++) {
            int j = (i + lane) & 15;
            int ch = ch0 + j;
            float v = fmaxf(0.f, o[j] * sA3[ch] + sB3[ch]);
            atomicMax(&smax[gl][ch], __float_as_uint(v));
        }
    }
    __syncthreads();
    for (int i = t; i < 1024; i += 256) {
        int g = i >> 7, ch = i & 127;
        int G = blockIdx.x * 8 + g;
        int b = G >> 11, s = G & 2047;
        out_np[((size_t)b * 128 + ch) * 2048 + s] = __uint_as_float(smax[g][ch]);
    }
}

// ---------------------------------------------------------------- fold BN
template <int C>
__global__ void finalize_kernel(const float* __restrict__ gstat,
                                const float* __restrict__ gamma,
                                const float* __restrict__ beta,
                                float* __restrict__ AB) {
    int t = threadIdx.x;
    if (t < C) {
        float mu  = gstat[t]     * CNT_INV;
        float ex2 = gstat[C + t] * CNT_INV;
        float var = ex2 - mu * mu;
        float A = gamma[t] * rsqrtf(var + 1e-5f);
        AB[t] = A; AB[C + t] = beta[t] - mu * A;
    }
}

// ---------------------------------------------------------------- launcher
extern "C" void kernel_launch(void* const* d_in, const int* in_sizes, int n_in,
                              void* d_out, int out_size, void* d_ws, size_t ws_size,
                              hipStream_t stream) {
    (void)in_sizes; (void)n_in; (void)out_size; (void)ws_size;
    const float* xyz    = (const float*)d_in[0];
    const float* points = (const float*)d_in[1];
    const float* w1 = (const float*)d_in[2],  *b1 = (const float*)d_in[3];
    const float* g1 = (const float*)d_in[4],  *be1 = (const float*)d_in[5];
    const float* w2 = (const float*)d_in[6],  *b2 = (const float*)d_in[7];
    const float* g2 = (const float*)d_in[8],  *be2 = (const float*)d_in[9];
    const float* w3 = (const float*)d_in[10], *b3 = (const float*)d_in[11];
    const float* g3 = (const float*)d_in[12], *be3 = (const float*)d_in[13];

    float* out    = (float*)d_out;                      // new_xyz (B,3,S)
    float* out_np = out + (size_t)BATCH * 3 * S_PTS;    // new_points (B,128,S)

    // ws: [0,2M) ballidx | [2M,+6K) stats/AB | [4M, 132M) xbuf (x1 -> x2 in place)
    char*  ws      = (char*)d_ws;
    int*   ballidx = (int*)ws;
    float* gbase   = (float*)(ws + (2ull << 20));
    float* gstat1  = gbase;
    float* gstat2  = gbase + 256;
    float* gstat3  = gbase + 512;
    float* AB1     = gbase + 768;
    float* AB2     = gbase + 896;
    float* AB3     = gbase + 1024;
    float* xbuf    = (float*)(ws + (4ull << 20));

    hipMemsetAsync(gstat1, 0, 768 * sizeof(float), stream);

    fps_kernel  <<<BATCH, 512, 0, stream>>>(xyz, out);
    ball_kernel <<<(BATCH * S_PTS) / 4, 256, 0, stream>>>(xyz, out, ballidx);
    d_conv1     <<<P_TOT / 256, 256, 0, stream>>>(xyz, points, out, ballidx, w1, b1, xbuf);
    d_stats<64> <<<P_TOT / 256, 256, 0, stream>>>(xbuf, gstat1);
    finalize_kernel<64><<<1, 64, 0, stream>>>(gstat1, g1, be1, AB1);
    d_conv2     <<<P_TOT / 256, 256, 0, stream>>>(xbuf, AB1, w2, b2);
    d_stats<64> <<<P_TOT / 256, 256, 0, stream>>>(xbuf, gstat2);
    finalize_kernel<64><<<1, 64, 0, stream>>>(gstat2, g2, be2, AB2);
    d_conv3_stats<<<P_TOT / 256, 256, 0, stream>>>(xbuf, AB2, w3, b3, gstat3);
    finalize_kernel<128><<<1, 128, 0, stream>>>(gstat3, g3, be3, AB3);
    d_conv3_max <<<P_TOT / 256, 256, 0, stream>>>(xbuf, AB2, w3, b3, AB3, out_np);
}

// Round 6
// 3468.475 us; speedup vs baseline: 1.4003x; 1.4003x over previous
//
#include <hip/hip_runtime.h>
#include <cstdint>

#define N_PTS   8192
#define S_PTS   2048
#define K_SMP   32
#define BATCH   8
#define P_TOT   (BATCH*S_PTS*K_SMP)   /* 524288 */
#define R2      0.16f
#define CNT_INV (1.0f/524288.0f)

// Unfused: matches numpy-f32 elementwise square + sequential 3-sum. PROVEN round 5.
__device__ __forceinline__ float sqd(float ax, float ay, float az,
                                     float bx, float by, float bz) {
    float dx = __fsub_rn(ax, bx), dy = __fsub_rn(ay, by), dz = __fsub_rn(az, bz);
    return __fadd_rn(__fadd_rn(__fmul_rn(dx, dx), __fmul_rn(dy, dy)), __fmul_rn(dz, dz));
}

// ---------------------------------------------------------------- FPS v2
// 256 thr (4 waves, 1/SIMD) x 32 pts. Reduce: DPP row_ror 1/2/4/8 (VALU-class,
// replaces the ds_bpermute shfl chain) -> 16 row partials (lanes l&15==0) ->
// one barrier -> every thread max-reduces 16 packed u64 keys itself (no
// atomic). Partials double-buffered (i&1) so one barrier/step is race-free.
// Key = bits(maxval)<<32 | ~idx : max=val, tie -> min idx (argmax semantics).
#define ROR_STEP(N)                                                                         \
    {                                                                                       \
        float ov = __int_as_float(__builtin_amdgcn_mov_dpp(__float_as_int(bv),              \
                                                           0x120|(N), 0xF, 0xF, true));     \
        int   oi = __builtin_amdgcn_mov_dpp(bi, 0x120|(N), 0xF, 0xF, true);                 \
        if (ov > bv || (ov == bv && oi < bi)) { bv = ov; bi = oi; }                         \
    }

__global__ __launch_bounds__(256) void fps_kernel(const float* __restrict__ xyz,
                                                  float* __restrict__ newxyz) {
    __shared__ float sx[N_PTS], sy[N_PTS], sz[N_PTS];      // 96 KiB (broadcast source)
    __shared__ unsigned long long s_part[2][16];           // row partials, dbuf
    __shared__ int s_sel[S_PTS];                           // 8 KiB

    const int b = blockIdx.x, t = threadIdx.x;
    const float* xb = xyz + (size_t)b * 3 * N_PTS;
    const int base = t * 32;

    float px[32], py[32], pz[32], dist[32];
#pragma unroll
    for (int q = 0; q < 8; q++) {
        float4 vx = *(const float4*)(xb + base + 4 * q);
        float4 vy = *(const float4*)(xb + N_PTS + base + 4 * q);
        float4 vz = *(const float4*)(xb + 2 * N_PTS + base + 4 * q);
        px[4*q] = vx.x; px[4*q+1] = vx.y; px[4*q+2] = vx.z; px[4*q+3] = vx.w;
        py[4*q] = vy.x; py[4*q+1] = vy.y; py[4*q+2] = vy.z; py[4*q+3] = vy.w;
        pz[4*q] = vz.x; pz[4*q+1] = vz.y; pz[4*q+2] = vz.z; pz[4*q+3] = vz.w;
    }
#pragma unroll
    for (int j = 0; j < 32; j++) {
        sx[base+j] = px[j]; sy[base+j] = py[j]; sz[base+j] = pz[j];
        dist[j] = 1e10f;
    }
    if (t == 0) s_sel[0] = 0;
    __syncthreads();

    int last = 0;
    for (int i = 1; i < S_PTS; i++) {
        float lx = sx[last], ly = sy[last], lz = sz[last];   // LDS broadcast
        float mv = -1.0f;
#pragma unroll
        for (int j = 0; j < 32; j++) {
            float d  = sqd(px[j], py[j], pz[j], lx, ly, lz);
            float nd = fminf(dist[j], d);
            dist[j] = nd;
            mv = fmaxf(mv, nd);
        }
        // find smallest local j with dist[j]==mv (descending scan, last write wins)
        int mi = base;
#pragma unroll
        for (int j = 31; j >= 0; j--) if (dist[j] == mv) mi = base + j;

        float bv = mv; int bi = mi;
        ROR_STEP(1) ROR_STEP(2) ROR_STEP(4) ROR_STEP(8)    // 16-lane row argmax
        if ((t & 15) == 0)
            s_part[i & 1][t >> 4] =
                ((unsigned long long)__float_as_uint(bv) << 32)
                | (unsigned long long)(0xFFFFFFFFu - (unsigned)bi);
        __syncthreads();
        unsigned long long best = s_part[i & 1][0];
#pragma unroll
        for (int r = 1; r < 16; r++) {
            unsigned long long k = s_part[i & 1][r];
            if (k > best) best = k;
        }
        last = (int)(0xFFFFFFFFu - (unsigned)(best & 0xFFFFFFFFull)) & (N_PTS - 1);
        if (t == 0) s_sel[i] = last;
    }
    __syncthreads();
    for (int s = t; s < S_PTS; s += 256) {
        int id = s_sel[s];
        newxyz[((size_t)b*3 + 0) * S_PTS + s] = sx[id];
        newxyz[((size_t)b*3 + 1) * S_PTS + s] = sy[id];
        newxyz[((size_t)b*3 + 2) * S_PTS + s] = sz[id];
    }
}

// ---------------------------------------------------------------- ball query (proven round 5)
__global__ __launch_bounds__(256) void ball_kernel(const float* __restrict__ xyz,
                                                   const float* __restrict__ newxyz,
                                                   int* __restrict__ ballidx) {
    int g    = blockIdx.x * 4 + (threadIdx.x >> 6);
    int lane = threadIdx.x & 63;
    int b = g >> 11, s = g & 2047;
    const float* xb = xyz + (size_t)b * 3 * N_PTS;
    float cx = newxyz[((size_t)b*3 + 0) * S_PTS + s];
    float cy = newxyz[((size_t)b*3 + 1) * S_PTS + s];
    float cz = newxyz[((size_t)b*3 + 2) * S_PTS + s];
    int* outp = ballidx + (size_t)g * K_SMP;

    int cnt = 0, first = 0;  bool have_first = false;
    for (int n0 = 0; n0 < N_PTS; n0 += 64) {
        int n = n0 + lane;
        float d = sqd(cx, cy, cz, xb[n], xb[N_PTS + n], xb[2*N_PTS + n]);
        bool in = (d <= R2);
        unsigned long long m = __ballot(in);
        if (in) {
            int pos = cnt + __popcll(m & ((1ull << lane) - 1ull));
            if (pos < K_SMP) outp[pos] = n;
        }
        if (!have_first && m != 0ull) { first = n0 + (int)__builtin_ctzll(m); have_first = true; }
        cnt += __popcll(m);
        if (cnt >= K_SMP) break;
    }
    if (cnt < K_SMP && lane < K_SMP && lane >= cnt) outp[lane] = first;
}

// ---------------------------------------------------------------- conv1 (proven round 5)
__global__ __launch_bounds__(256) void d_conv1(const float* __restrict__ xyz,
                                               const float* __restrict__ points,
                                               const float* __restrict__ newxyz,
                                               const int* __restrict__ ballidx,
                                               const float* __restrict__ w1,
                                               const float* __restrict__ b1,
                                               float* __restrict__ xbuf) {
    __shared__ float sw[64 * 9];
    __shared__ float sb[64];
    int t = threadIdx.x;
    for (int i = t; i < 576; i += 256) sw[i] = w1[i];
    if (t < 64) sb[t] = b1[t];
    __syncthreads();

    int p = blockIdx.x * 256 + t;
    int g = p >> 5, b = g >> 11, s = g & 2047;
    int idx = ballidx[p] & (N_PTS - 1);
    const float* xb = xyz    + (size_t)b * 3 * N_PTS;
    const float* pb = points + (size_t)b * 6 * N_PTS;
    float f[9];
    f[0] = xb[idx]           - newxyz[((size_t)b*3 + 0) * S_PTS + s];
    f[1] = xb[N_PTS + idx]   - newxyz[((size_t)b*3 + 1) * S_PTS + s];
    f[2] = xb[2*N_PTS + idx] - newxyz[((size_t)b*3 + 2) * S_PTS + s];
#pragma unroll
    for (int c = 0; c < 6; c++) f[3 + c] = pb[c * N_PTS + idx];

    float* row = xbuf + (size_t)p * 64;
    for (int co = 0; co < 64; co++) {
        float a = sb[co];
#pragma unroll
        for (int c = 0; c < 9; c++) a += sw[co * 9 + c] * f[c];
        row[co] = a;
    }
}

// ---------------------------------------------------------------- stats (proven round 5)
template <int C>
__global__ __launch_bounds__(256) void d_stats(const float* __restrict__ x,
                                               float* __restrict__ gstat) {
    __shared__ float ss[C], sq[C];
    int t = threadIdx.x;
    for (int i = t; i < C; i += 256) { ss[i] = 0.f; sq[i] = 0.f; }
    __syncthreads();
    int c = t & (C - 1), r0 = t / C;
    const int RPI = 256 / C;
    float s = 0.f, q = 0.f;
    size_t base = (size_t)blockIdx.x * 256;
    for (int r = r0; r < 256; r += RPI) {
        float v = x[(base + r) * C + c];
        s += v; q += v * v;
    }
    atomicAdd(&ss[c], s); atomicAdd(&sq[c], q);
    __syncthreads();
    for (int i = t; i < C; i += 256) { atomicAdd(&gstat[i], ss[i]); atomicAdd(&gstat[C + i], sq[i]); }
}

// ---------------------------------------------------------------- conv2 v2: BN1+relu + conv2, in place
// Thread owns 2 FULL rows (exclusive -> in-place safe). Weights [c][co] in LDS,
// one b128 read feeds 8 FMA (2 rows x 4 couts).
__global__ __launch_bounds__(256) void c2_kernel(float* __restrict__ xbuf,
                                                 const float* __restrict__ AB1,
                                                 const float* __restrict__ w2,
                                                 const float* __restrict__ b2) {
    __shared__ __align__(16) float wt[64 * 64];   // [c][co]
    __shared__ float sA[64], sB[64], sb[64];
    int t = threadIdx.x;
    for (int i = t; i < 4096; i += 256) { int co = i & 63, c = i >> 6; wt[c*64+co] = w2[co*64+c]; }
    if (t < 64) { sA[t] = AB1[t]; sB[t] = AB1[64 + t]; sb[t] = b2[t]; }
    __syncthreads();

    size_t p0 = (size_t)blockIdx.x * 512 + t, p1 = p0 + 256;
    float* r0 = xbuf + p0 * 64;
    float* r1 = xbuf + p1 * 64;

    float acc0[64], acc1[64];
#pragma unroll
    for (int co = 0; co < 64; co++) { float bv = sb[co]; acc0[co] = bv; acc1[co] = bv; }

#pragma unroll
    for (int c0 = 0; c0 < 64; c0 += 8) {
        float ya[8], yb[8];
#pragma unroll
        for (int q = 0; q < 8; q += 4) {
            float4 va = *(const float4*)(r0 + c0 + q);
            float4 vb = *(const float4*)(r1 + c0 + q);
            ya[q] = va.x; ya[q+1] = va.y; ya[q+2] = va.z; ya[q+3] = va.w;
            yb[q] = vb.x; yb[q+1] = vb.y; yb[q+2] = vb.z; yb[q+3] = vb.w;
        }
#pragma unroll
        for (int q = 0; q < 8; q++) {
            ya[q] = fmaxf(0.f, ya[q] * sA[c0+q] + sB[c0+q]);
            yb[q] = fmaxf(0.f, yb[q] * sA[c0+q] + sB[c0+q]);
        }
#pragma unroll
        for (int c = 0; c < 8; c++) {
            float fa = ya[c], fb = yb[c];
#pragma unroll
            for (int co = 0; co < 64; co += 4) {
                float4 w = *(const float4*)&wt[(c0+c)*64 + co];
                acc0[co]   += w.x * fa; acc0[co+1] += w.y * fa;
                acc0[co+2] += w.z * fa; acc0[co+3] += w.w * fa;
                acc1[co]   += w.x * fb; acc1[co+1] += w.y * fb;
                acc1[co+2] += w.z * fb; acc1[co+3] += w.w * fb;
            }
        }
    }
#pragma unroll
    for (int co = 0; co < 64; co += 4) {
        *(float4*)(r0 + co) = make_float4(acc0[co], acc0[co+1], acc0[co+2], acc0[co+3]);
        *(float4*)(r1 + co) = make_float4(acc1[co], acc1[co+1], acc1[co+2], acc1[co+3]);
    }
}

// ---------------------------------------------------------------- conv3 core: 4 pos x 32-cout quarter
// quarter = t&3 selects couts [quarter*32, +32); q = t>>2 selects base row.
// Positions p_i = blk*256 + q + 64*i. One b128 weight read feeds 16 FMA.
#define C3_COMPUTE(ACC)                                                                    \
    int quarter = t & 3, q = t >> 2, cb = quarter * 32;                                    \
    size_t pB = (size_t)blockIdx.x * 256 + q;                                              \
    const float* r0 = xbuf + (pB +   0) * 64;                                              \
    const float* r1 = xbuf + (pB +  64) * 64;                                              \
    const float* r2 = xbuf + (pB + 128) * 64;                                              \
    const float* r3 = xbuf + (pB + 192) * 64;                                              \
    float ACC[4][32];                                                                      \
    _Pragma("unroll")                                                                      \
    for (int co = 0; co < 32; co++) {                                                      \
        float bv = sb3[cb + co];                                                           \
        ACC[0][co] = bv; ACC[1][co] = bv; ACC[2][co] = bv; ACC[3][co] = bv;                \
    }                                                                                      \
    _Pragma("unroll")                                                                      \
    for (int c0 = 0; c0 < 64; c0 += 8) {                                                   \
        float y[4][8];                                                                     \
        _Pragma("unroll")                                                                  \
        for (int qq = 0; qq < 8; qq += 4) {                                                \
            float4 v0 = *(const float4*)(r0 + c0 + qq);                                    \
            float4 v1 = *(const float4*)(r1 + c0 + qq);                                    \
            float4 v2 = *(const float4*)(r2 + c0 + qq);                                    \
            float4 v3 = *(const float4*)(r3 + c0 + qq);                                    \
            y[0][qq] = v0.x; y[0][qq+1] = v0.y; y[0][qq+2] = v0.z; y[0][qq+3] = v0.w;      \
            y[1][qq] = v1.x; y[1][qq+1] = v1.y; y[1][qq+2] = v1.z; y[1][qq+3] = v1.w;      \
            y[2][qq] = v2.x; y[2][qq+1] = v2.y; y[2][qq+2] = v2.z; y[2][qq+3] = v2.w;      \
            y[3][qq] = v3.x; y[3][qq+1] = v3.y; y[3][qq+2] = v3.z; y[3][qq+3] = v3.w;      \
        }                                                                                  \
        _Pragma("unroll")                                                                  \
        for (int qq = 0; qq < 8; qq++) {                                                   \
            float A = sA[c0+qq], Bv = sB[c0+qq];                                           \
            y[0][qq] = fmaxf(0.f, y[0][qq] * A + Bv);                                      \
            y[1][qq] = fmaxf(0.f, y[1][qq] * A + Bv);                                      \
            y[2][qq] = fmaxf(0.f, y[2][qq] * A + Bv);                                      \
            y[3][qq] = fmaxf(0.f, y[3][qq] * A + Bv);                                      \
        }                                                                                  \
        _Pragma("unroll")                                                                  \
        for (int c = 0; c < 8; c++) {                                                      \
            float f0 = y[0][c], f1 = y[1][c], f2 = y[2][c], f3 = y[3][c];                  \
            _Pragma("unroll")                                                              \
            for (int co = 0; co < 32; co += 4) {                                           \
                float4 w = *(const float4*)&wt[(c0+c)*128 + cb + co];                      \
                ACC[0][co]   += w.x * f0; ACC[0][co+1] += w.y * f0;                        \
                ACC[0][co+2] += w.z * f0; ACC[0][co+3] += w.w * f0;                        \
                ACC[1][co]   += w.x * f1; ACC[1][co+1] += w.y * f1;                        \
                ACC[1][co+2] += w.z * f1; ACC[1][co+3] += w.w * f1;                        \
                ACC[2][co]   += w.x * f2; ACC[2][co+1] += w.y * f2;                        \
                ACC[2][co+2] += w.z * f2; ACC[2][co+3] += w.w * f2;                        \
                ACC[3][co]   += w.x * f3; ACC[3][co+1] += w.y * f3;                        \
                ACC[3][co+2] += w.z * f3; ACC[3][co+3] += w.w * f3;                        \
            }                                                                              \
        }                                                                                  \
    }

// conv3 pass A: stats. Epilogue: static-index LDS atomicAdd (sum over 4 pos in reg first).
__global__ __launch_bounds__(256) void c3_stats(const float* __restrict__ xbuf,
                                                const float* __restrict__ AB2,
                                                const float* __restrict__ w3,
                                                const float* __restrict__ b3,
                                                float* __restrict__ gstat) {
    __shared__ __align__(16) float wt[64 * 128];  // [c][ch] 32 KiB
    __shared__ float sA[64], sB[64], sb3[128], ss[128], sq[128];
    int t = threadIdx.x;
    for (int i = t; i < 8192; i += 256) { int ch = i & 127, c = i >> 7; wt[c*128+ch] = w3[ch*64+c]; }
    if (t < 64) { sA[t] = AB2[t]; sB[t] = AB2[64 + t]; }
    if (t < 128) { sb3[t] = b3[t]; ss[t] = 0.f; sq[t] = 0.f; }
    __syncthreads();

    C3_COMPUTE(acc)

#pragma unroll
    for (int co = 0; co < 32; co++) {
        float s  = acc[0][co] + acc[1][co] + acc[2][co] + acc[3][co];
        float qq = acc[0][co]*acc[0][co] + acc[1][co]*acc[1][co]
                 + acc[2][co]*acc[2][co] + acc[3][co]*acc[3][co];
        atomicAdd(&ss[cb + co], s);
        atomicAdd(&sq[cb + co], qq);
    }
    __syncthreads();
    if (t < 128) { atomicAdd(&gstat[t], ss[t]); atomicAdd(&gstat[128 + t], sq[t]); }
}

// conv3 pass B: recompute + BN3+relu + max over K via LDS uint atomicMax
// (relu >= 0 -> float bits monotonic; init 0). Static indices only.
__global__ __launch_bounds__(256) void c3_max(const float* __restrict__ xbuf,
                                              const float* __restrict__ AB2,
                                              const float* __restrict__ w3,
                                              const float* __restrict__ b3,
                                              const float* __restrict__ AB3,
                                              float* __restrict__ out_np) {
    __shared__ __align__(16) float wt[64 * 128];
    __shared__ float sA[64], sB[64], sb3[128], sA3[128], sB3[128];
    __shared__ unsigned int smax[8][128];
    int t = threadIdx.x;
    for (int i = t; i < 8192; i += 256) { int ch = i & 127, c = i >> 7; wt[c*128+ch] = w3[ch*64+c]; }
    if (t < 64) { sA[t] = AB2[t]; sB[t] = AB2[64 + t]; }
    if (t < 128) { sb3[t] = b3[t]; sA3[t] = AB3[t]; sB3[t] = AB3[128 + t]; }
    for (int i = t; i < 1024; i += 256) smax[i >> 7][i & 127] = 0u;
    __syncthreads();

    C3_COMPUTE(acc)

    // groups: p_i = blk*256 + q + 64i -> local group 2i + (q>>5)
    int g0 = (q >> 5);
#pragma unroll
    for (int co = 0; co < 32; co++) {
        int ch = cb + co;
        float A = sA3[ch], Bv = sB3[ch];
        float v0 = fmaxf(0.f, acc[0][co] * A + Bv);
        float v1 = fmaxf(0.f, acc[1][co] * A + Bv);
        float v2 = fmaxf(0.f, acc[2][co] * A + Bv);
        float v3 = fmaxf(0.f, acc[3][co] * A + Bv);
        atomicMax(&smax[g0    ][ch], __float_as_uint(v0));
        atomicMax(&smax[g0 + 2][ch], __float_as_uint(v1));
        atomicMax(&smax[g0 + 4][ch], __float_as_uint(v2));
        atomicMax(&smax[g0 + 6][ch], __float_as_uint(v3));
    }
    __syncthreads();
    for (int i = t; i < 1024; i += 256) {
        int g = i >> 7, ch = i & 127;
        int G = blockIdx.x * 8 + g;
        int b = G >> 11, s = G & 2047;
        out_np[((size_t)b * 128 + ch) * 2048 + s] = __uint_as_float(smax[g][ch]);
    }
}

// ---------------------------------------------------------------- fold BN
template <int C>
__global__ void finalize_kernel(const float* __restrict__ gstat,
                                const float* __restrict__ gamma,
                                const float* __restrict__ beta,
                                float* __restrict__ AB) {
    int t = threadIdx.x;
    if (t < C) {
        float mu  = gstat[t]     * CNT_INV;
        float ex2 = gstat[C + t] * CNT_INV;
        float var = ex2 - mu * mu;
        float A = gamma[t] * rsqrtf(var + 1e-5f);
        AB[t] = A; AB[C + t] = beta[t] - mu * A;
    }
}

// ---------------------------------------------------------------- launcher
extern "C" void kernel_launch(void* const* d_in, const int* in_sizes, int n_in,
                              void* d_out, int out_size, void* d_ws, size_t ws_size,
                              hipStream_t stream) {
    (void)in_sizes; (void)n_in; (void)out_size; (void)ws_size;
    const float* xyz    = (const float*)d_in[0];
    const float* points = (const float*)d_in[1];
    const float* w1 = (const float*)d_in[2],  *b1 = (const float*)d_in[3];
    const float* g1 = (const float*)d_in[4],  *be1 = (const float*)d_in[5];
    const float* w2 = (const float*)d_in[6],  *b2 = (const float*)d_in[7];
    const float* g2 = (const float*)d_in[8],  *be2 = (const float*)d_in[9];
    const float* w3 = (const float*)d_in[10], *b3 = (const float*)d_in[11];
    const float* g3 = (const float*)d_in[12], *be3 = (const float*)d_in[13];

    float* out    = (float*)d_out;                      // new_xyz (B,3,S)
    float* out_np = out + (size_t)BATCH * 3 * S_PTS;    // new_points (B,128,S)

    // ws: [0,2M) ballidx | [2M,+6K) stats/AB | [4M, 132M) xbuf (proven size)
    char*  ws      = (char*)d_ws;
    int*   ballidx = (int*)ws;
    float* gbase   = (float*)(ws + (2ull << 20));
    float* gstat1  = gbase;
    float* gstat2  = gbase + 256;
    float* gstat3  = gbase + 512;
    float* AB1     = gbase + 768;
    float* AB2     = gbase + 896;
    float* AB3     = gbase + 1024;
    float* xbuf    = (float*)(ws + (4ull << 20));

    hipMemsetAsync(gstat1, 0, 768 * sizeof(float), stream);

    fps_kernel  <<<BATCH, 256, 0, stream>>>(xyz, out);
    ball_kernel <<<(BATCH * S_PTS) / 4, 256, 0, stream>>>(xyz, out, ballidx);
    d_conv1     <<<P_TOT / 256, 256, 0, stream>>>(xyz, points, out, ballidx, w1, b1, xbuf);
    d_stats<64> <<<P_TOT / 256, 256, 0, stream>>>(xbuf, gstat1);
    finalize_kernel<64><<<1, 64, 0, stream>>>(gstat1, g1, be1, AB1);
    c2_kernel   <<<P_TOT / 512, 256, 0, stream>>>(xbuf, AB1, w2, b2);
    d_stats<64> <<<P_TOT / 256, 256, 0, stream>>>(xbuf, gstat2);
    finalize_kernel<64><<<1, 64, 0, stream>>>(gstat2, g2, be2, AB2);
    c3_stats    <<<P_TOT / 256, 256, 0, stream>>>(xbuf, AB2, w3, b3, gstat3);
    finalize_kernel<128><<<1, 128, 0, stream>>>(gstat3, g3, be3, AB3);
    c3_max      <<<P_TOT / 256, 256, 0, stream>>>(xbuf, AB2, w3, b3, AB3, out_np);
}